// Round 5
// baseline (112.350 us; speedup 1.0000x reference)
//
#include <hip/hip_runtime.h>
#include <math.h>

// Problem constants (fixed by setup_inputs): B=4, N=M=P=2048, NS=1024.
// out = [4,2048,2048] fp32, out_size = 16777216 floats.
//
// Pipeline (3 kernels):
//  1. nn_kernel<<<416>>>: each block = 2048 a-points (8/thread) x 256 b-points
//     (LDS, float4 = x,y,z,-0.5|b|^2). Inner loop in <2 x float> packed form
//     (v_pk_fma_f32). Writes 2048 partial clamped-d2 values (min over ITS
//     b-tile) to a 3.4 MB partial array in the TAIL of d_out.
//     Partial slot for block bid = [bid*2048, +2048).
//  2. reduce_kernel<<<36>>>: per point, min over its b-tile partials
//     (coalesced gather), sqrt / conf-MSE, per-block scaled sum -> ws[blk].
//  3. out_kernel<<<1024>>>: S = sum(ws[0..35]);
//     out[b,n,m] = S + 0.5*dist(pc1_0[b,n], pc2[b,m]). Overwrites the
//     partial tail last; never reads d_out.
//
// nn job table (416 blocks; a_tile = local / b_tiles, b_tile = local % b_tiles):
//   [0,128)    cd:   A=pc1_0(8192) vs B=pc2(8192)    4 at x 32 bt
//   [128,256)  cd:   A=pc2(8192)   vs B=pc1_0(8192)  4 at x 32 bt
//   [256,320)  seed: A=pc1_1(4096) vs B=pc2(8192)    2 at x 32 bt
//   [320,384)  seed: A=pc2(8192)   vs B=pc1_1(4096)  4 at x 16 bt
//   [384,416)  conf: A=pc3[b](2048) vs B=pc2[b](2048) per batch: 1 at x 8 bt

constexpr int OUT_TOTAL  = 4 * 2048 * 2048;
constexpr int PART_TOTAL = 416 * 2048;              // 851968 floats, 3.4 MB
constexpr int PART_OFS   = OUT_TOTAL - PART_TOTAL;

// native vector types (HIP_vector_type rejected by nontemporal builtin; f2 for pk math)
typedef float nfloat4 __attribute__((ext_vector_type(4)));
typedef float f2 __attribute__((ext_vector_type(2)));

__global__ __launch_bounds__(256) void nn_kernel(
    const float* __restrict__ A0,   // pc1_0 flat (8192 pts)
    const float* __restrict__ A1,   // pc1_1 flat (4096 pts)
    const float* __restrict__ P2,   // pc2   flat (8192 pts / 4 batches x 2048)
    const float* __restrict__ P3,   // pc3   (4 x 2048 pts)
    float* __restrict__ part)
{
    __shared__ float4 lds[256];     // (bx, by, bz, -0.5*|b|^2)
    int bid = blockIdx.x;
    const float* A; const float* Bp; int b_tiles; int local;
    if (bid < 128)      { local = bid;       A = A0; Bp = P2; b_tiles = 32; }
    else if (bid < 256) { local = bid - 128; A = P2; Bp = A0; b_tiles = 32; }
    else if (bid < 320) { local = bid - 256; A = A1; Bp = P2; b_tiles = 32; }
    else if (bid < 384) { local = bid - 320; A = P2; Bp = A1; b_tiles = 16; }
    else { int l2 = bid - 384; int bt = l2 >> 3; local = l2 & 7;
           A = P3 + bt * 6144; Bp = P2 + bt * 6144; b_tiles = 8; }
    int a_tile = local / b_tiles;
    int b_tile = local - a_tile * b_tiles;

    {
        const float* s = Bp + (b_tile * 256 + threadIdx.x) * 3;
        float bx = s[0], by = s[1], bz = s[2];
        float nb2 = -0.5f * fmaf(bx, bx, fmaf(by, by, bz * bz));
        lds[threadIdx.x] = make_float4(bx, by, bz, nb2);
    }

    // 8 a-points per thread (24 consecutive floats, 16B-aligned -> 6x float4)
    int a_base = a_tile * 2048 + threadIdx.x * 8;
    const float4* av = (const float4*)(A + a_base * 3);
    float f[24];
    #pragma unroll
    for (int t = 0; t < 6; t++) {
        float4 q = av[t];
        f[4*t] = q.x; f[4*t+1] = q.y; f[4*t+2] = q.z; f[4*t+3] = q.w;
    }
    f2 ax2[4], ay2[4], az2[4], mx2[4];
    #pragma unroll
    for (int p = 0; p < 4; p++) {
        ax2[p] = (f2){f[6*p+0], f[6*p+3]};
        ay2[p] = (f2){f[6*p+1], f[6*p+4]};
        az2[p] = (f2){f[6*p+2], f[6*p+5]};
        mx2[p] = (f2){-3.4e38f, -3.4e38f};
    }
    __syncthreads();

    // maximize (a.b - 0.5|b|^2) over b; d2 = max(|a|^2 - 2*mx, 0).
    // Packed pairs: 3 v_pk_fma_f32 + 2 v_max_f32 per 2 pairs.
    #pragma unroll 4
    for (int j = 0; j < 256; j++) {
        float4 b = lds[j];
        f2 bx2 = {b.x, b.x}, by2 = {b.y, b.y}, bz2 = {b.z, b.z}, bw2 = {b.w, b.w};
        #pragma unroll
        for (int p = 0; p < 4; p++) {
            f2 u = __builtin_elementwise_fma(az2[p], bz2, bw2);
            u = __builtin_elementwise_fma(ay2[p], by2, u);
            u = __builtin_elementwise_fma(ax2[p], bx2, u);
            mx2[p] = __builtin_elementwise_max(mx2[p], u);
        }
    }
    float o[8];
    #pragma unroll
    for (int p = 0; p < 4; p++) {
        #pragma unroll
        for (int h = 0; h < 2; h++) {
            float axx = ax2[p][h], ayy = ay2[p][h], azz = az2[p][h];
            float a2 = fmaf(axx, axx, fmaf(ayy, ayy, azz * azz));
            o[2*p+h] = fmaxf(fmaf(-2.f, mx2[p][h], a2), 0.f);
        }
    }
    float* dst = part + bid * 2048 + threadIdx.x * 8;
    *(float4*)(dst)     = make_float4(o[0], o[1], o[2], o[3]);
    *(float4*)(dst + 4) = make_float4(o[4], o[5], o[6], o[7]);
}

// 36 blocks x 1024 points. Point slice -> (first tile-block pbb, tile count bt,
// in-tile offset ofs). a-tiles are 2048 points = 2 reduce slices each.
__global__ __launch_bounds__(256) void reduce_kernel(
    const float* __restrict__ part,
    const float* __restrict__ conf_in,   // pc1_3, 8192 values
    float* __restrict__ ws)
{
    int blk = blockIdx.x;
    int tid = threadIdx.x;
    int pbb, bt, ofs;
    if (blk < 8)       { int l = blk;      pbb = 0   + (l >> 1) * 32; bt = 32; ofs = (l & 1) << 10; }
    else if (blk < 16) { int l = blk - 8;  pbb = 128 + (l >> 1) * 32; bt = 32; ofs = (l & 1) << 10; }
    else if (blk < 20) { int l = blk - 16; pbb = 256 + (l >> 1) * 32; bt = 32; ofs = (l & 1) << 10; }
    else if (blk < 28) { int l = blk - 20; pbb = 320 + (l >> 1) * 16; bt = 16; ofs = (l & 1) << 10; }
    else               { int l = blk - 28; pbb = 384 + (l >> 1) * 8;  bt = 8;  ofs = (l & 1) << 10; }

    float m0 = 3.4e38f, m1 = 3.4e38f, m2 = 3.4e38f, m3 = 3.4e38f;
    const float* p = part + (pbb << 11) + ofs + tid;
    #pragma unroll 4
    for (int t = 0; t < bt; t++, p += 2048) {
        m0 = fminf(m0, p[0]);
        m1 = fminf(m1, p[256]);
        m2 = fminf(m2, p[512]);
        m3 = fminf(m3, p[768]);
    }
    float d0 = sqrtf(m0), d1 = sqrtf(m1), d2 = sqrtf(m2), d3 = sqrtf(m3);
    float sum;
    if (blk < 28) {
        sum = (d0 + d1) + (d2 + d3);
    } else {
        const float* c = conf_in + (blk - 28) * 1024 + tid;
        float e0 = c[0]   - __expf(-d0);
        float e1 = c[256] - __expf(-d1);
        float e2 = c[512] - __expf(-d2);
        float e3 = c[768] - __expf(-d3);
        sum = fmaf(e0, e0, e1 * e1) + fmaf(e2, e2, e3 * e3);
    }
    #pragma unroll
    for (int ofs2 = 32; ofs2 > 0; ofs2 >>= 1) sum += __shfl_down(sum, ofs2);
    __shared__ float red[4];
    if ((tid & 63) == 0) red[tid >> 6] = sum;
    __syncthreads();
    if (tid == 0) {
        float tot = (red[0] + red[1]) + (red[2] + red[3]);
        float scale = (blk < 16) ? 0.5f / 8192.f
                    : (blk < 20) ? 1.f / 4096.f
                    :              1.f / 8192.f;
        ws[blk] = tot * scale;
    }
}

// out[b,n,m] = S + 0.5 * dist(pc1_0[b,n], pc2[b,m]).
// Block = (batch, group of 8 n-rows). Thread owns m = tid*4..+3 and
// 1024+tid*4..+3 (8 pc2 points in registers); nontemporal float4 stores.
__global__ __launch_bounds__(256) void out_kernel(
    const float* __restrict__ pc1_0,
    const float* __restrict__ pc2,
    const float* __restrict__ wsp,
    float* __restrict__ out)
{
    int blk = blockIdx.x;            // 1024 blocks
    int batch = blk >> 8;
    int n8 = blk & 255;
    int tid = threadIdx.x;
    float S = 0.f;
    #pragma unroll
    for (int t = 0; t < 36; t++) S += wsp[t];   // uniform -> s_loads
    const float* bb = pc2 + batch * 6144;
    float bx[8], by[8], bz[8];
    {
        const float4* p = (const float4*)(bb + tid * 12);
        float4 u0 = p[0], u1 = p[1], u2 = p[2];
        bx[0]=u0.x; by[0]=u0.y; bz[0]=u0.z;
        bx[1]=u0.w; by[1]=u1.x; bz[1]=u1.y;
        bx[2]=u1.z; by[2]=u1.w; bz[2]=u2.x;
        bx[3]=u2.y; by[3]=u2.z; bz[3]=u2.w;
    }
    {
        const float4* p = (const float4*)(bb + 3072 + tid * 12);
        float4 u0 = p[0], u1 = p[1], u2 = p[2];
        bx[4]=u0.x; by[4]=u0.y; bz[4]=u0.z;
        bx[5]=u0.w; by[5]=u1.x; bz[5]=u1.y;
        bx[6]=u1.z; by[6]=u1.w; bz[6]=u2.x;
        bx[7]=u2.y; by[7]=u2.z; bz[7]=u2.w;
    }
    const float* arow = pc1_0 + batch * 6144 + n8 * 24;  // 8 rows x 3 (uniform)
    float* ob = out + (long)((batch << 11) + (n8 << 3)) * 2048 + tid * 4;
    #pragma unroll
    for (int r = 0; r < 8; r++) {
        float axx = arow[r*3], ayy = arow[r*3+1], azz = arow[r*3+2];
        float o[8];
        #pragma unroll
        for (int k = 0; k < 8; k++) {
            float dx = axx - bx[k], dy = ayy - by[k], dz = azz - bz[k];
            float d2 = fmaf(dx, dx, fmaf(dy, dy, dz*dz));
            o[k] = fmaf(0.5f, sqrtf(d2), S);
        }
        nfloat4 lo = { o[0], o[1], o[2], o[3] };
        nfloat4 hi = { o[4], o[5], o[6], o[7] };
        __builtin_nontemporal_store(lo, (nfloat4*)(ob + r * 2048));
        __builtin_nontemporal_store(hi, (nfloat4*)(ob + r * 2048 + 1024));
    }
}

extern "C" void kernel_launch(void* const* d_in, const int* in_sizes, int n_in,
                              void* d_out, int out_size, void* d_ws, size_t ws_size,
                              hipStream_t stream) {
    const float* pc1_0 = (const float*)d_in[0];  // [4,2048,3]
    const float* pc1_1 = (const float*)d_in[1];  // [4,1024,3]
    const float* pc1_3 = (const float*)d_in[2];  // [4,2048,1]
    const float* pc2   = (const float*)d_in[3];  // [4,2048,3]
    const float* pc3   = (const float*)d_in[4];  // [4,2048,3]
    float* out = (float*)d_out;
    float* ws  = (float*)d_ws;                   // ws[0..35]: scaled partial sums
    float* part = out + PART_OFS;                // partial-min scratch in d_out tail

    nn_kernel<<<416, 256, 0, stream>>>(pc1_0, pc1_1, pc2, pc3, part);
    reduce_kernel<<<36, 256, 0, stream>>>(part, pc1_3, ws);
    out_kernel<<<1024, 256, 0, stream>>>(pc1_0, pc2, ws, out);
}